// Round 1
// baseline (18.502 us; speedup 1.0000x reference)
//
#include <hip/hip_runtime.h>

// Problem constants (from reference): B=32, N=64, T=50, F=2, E=8
// M = B*T*N graphs-of-nodes; we only need node 0 of each (b,t) graph.
// out layout: [0,3200)   = inputs = x[:,0]          shape (B,T,F)
//             [3200,16000) = enc_sp = enc[:,:,0,:]  shape (B,T,E)

__global__ __launch_bounds__(64) void encoder_spatial_kernel(
    const float* __restrict__ x,      // (B,N,T,F) = (32,64,50,2)
    const float* __restrict__ W_res,  // (F,E) = (2,8)
    const float* __restrict__ W_gcn,  // (2,8)
    const float* __restrict__ b_gcn,  // (8,)
    float* __restrict__ out)          // 16000 floats
{
    constexpr int N = 64, T = 50, F = 2, E = 8;
    const int g    = blockIdx.x;       // graph id = b*T + t
    const int b    = g / T;
    const int t    = g % T;
    const int lane = threadIdx.x;      // node index 0..63 (one wave)

    // node `lane` position: x[b, lane, t, 0..1]
    const float* base = x + ((size_t)b * N * T + (size_t)lane * T + t) * F;
    const float px = base[0];
    const float py = base[1];

    __shared__ float sx[64], sy[64];
    sx[lane] = px;
    sy[lane] = py;
    __syncthreads();

    // Phase 1: degree of node `lane`; also save w(lane, 0)
    float deg = 1.0f;
    float w0  = 0.0f;
    #pragma unroll
    for (int k = 0; k < 64; ++k) {
        if (k == lane) continue;
        const float dx = px - sx[k];
        const float dy = py - sy[k];
        float dist = sqrtf(dx * dx + dy * dy);
        if (dist == 0.0f) dist = 1e-6f;
        const float w = fminf(1.0f / dist, 1.0f);
        deg += w;
        if (k == 0) w0 = w;
    }
    const float dinv = 1.0f / sqrtf(deg);

    // Phase 2: c_i = dinv_i * w(i,0) for i != 0; reduce sum(c*px), sum(c*py)
    const float c = (lane == 0) ? 0.0f : dinv * w0;
    float cx = c * px;
    float cy = c * py;
    #pragma unroll
    for (int off = 32; off > 0; off >>= 1) {
        cx += __shfl_xor(cx, off, 64);
        cy += __shfl_xor(cy, off, 64);
    }
    // butterfly leaves the full sum in every lane

    const float dinv0 = __shfl(dinv, 0, 64);
    const float px0   = sx[0];
    const float py0   = sy[0];

    if (lane < E) {
        const int e = lane;
        const float wg0 = W_gcn[e];          // W_gcn[0][e]
        const float wg1 = W_gcn[E + e];      // W_gcn[1][e]
        // agg = dinv0 * sum_{i!=0}(dinv_i w_i0 h_i) + dinv0^2 * h_0
        float agg = dinv0 * (cx * wg0 + cy * wg1)
                  + dinv0 * dinv0 * (px0 * wg0 + py0 * wg1);
        float enc = agg + b_gcn[e] + px0 * W_res[e] + py0 * W_res[E + e];
        enc = fmaxf(enc, 0.0f);
        out[3200 + g * E + e] = enc;
    }
    if (lane < F) {
        // inputs output: x[b, 0, t, lane] == node-0 position component
        out[g * F + lane] = (lane == 0) ? px0 : py0;
    }
}

extern "C" void kernel_launch(void* const* d_in, const int* in_sizes, int n_in,
                              void* d_out, int out_size, void* d_ws, size_t ws_size,
                              hipStream_t stream) {
    const float* x     = (const float*)d_in[0];
    const float* W_res = (const float*)d_in[1];
    const float* W_gcn = (const float*)d_in[2];
    const float* b_gcn = (const float*)d_in[3];
    float* out = (float*)d_out;

    const int num_graphs = 32 * 50;  // B*T
    encoder_spatial_kernel<<<num_graphs, 64, 0, stream>>>(x, W_res, W_gcn, b_gcn, out);
}

// Round 2
// 9.693 us; speedup vs baseline: 1.9088x; 1.9088x over previous
//
#include <hip/hip_runtime.h>

// Problem constants: B=32, N=64, T=50, F=2, E=8.
// Only node 0 of each (b,t) graph reaches the output:
//   out[0:3200)      = x[:,0]              (B,T,F)
//   out[3200:16000)  = enc[:,:,0,:]        (B,T,E)
//
// Per graph: deg_i = 1 + sum_{k!=i} min(1/dist(i,k),1)  == sum_all_k w(i,k)
// with w(i,i)=rsq(0)->min(inf,1)=1 supplying the +1.
// agg[0] = dinv0 * sum_{i!=0} dinv_i*w(i,0)*h_i + dinv0^2*h_0,  h_i = p_i @ W_gcn.
// Since F=2 the neighbor sum collapses to two scalars (sum c*px, sum c*py).

__global__ __launch_bounds__(64) void encoder_spatial_kernel(
    const float* __restrict__ x,      // (B,N,T,F)
    const float* __restrict__ W_res,  // (2,8)
    const float* __restrict__ W_gcn,  // (2,8)
    const float* __restrict__ b_gcn,  // (8,)
    float* __restrict__ out)          // 16000 floats
{
    constexpr int N = 64, T = 50, F = 2, E = 8;
    const int g    = blockIdx.x;      // b*T + t
    const int b    = g / T;
    const int t    = g % T;
    const int lane = threadIdx.x;     // node 0..63, one wave per block

    // x[b, lane, t, 0:2] — element index is even -> 8B aligned
    const float2 p = *reinterpret_cast<const float2*>(
        x + ((size_t)(b * N + lane) * T + t) * F);

    __shared__ float2 sp[64];
    sp[lane] = p;
    __syncthreads();

    // deg (includes self-term == the +1) and w(lane, 0)
    float deg = 0.0f;
    float w0  = 0.0f;
    #pragma unroll
    for (int k = 0; k < 64; ++k) {
        const float2 q = sp[k];
        const float dx = p.x - q.x;
        const float dy = p.y - q.y;
        const float d2 = dx * dx + dy * dy;
        // rsq(0)=+inf -> min gives 1: covers both self-term and dist==0 case
        const float w = fminf(__builtin_amdgcn_rsqf(d2), 1.0f);
        deg += w;
        if (k == 0) w0 = w;   // unrolled: no runtime branch
    }
    const float dinv = __builtin_amdgcn_rsqf(deg);   // deg >= 1

    // c_i = dinv_i * w(i,0), zero for i==0; reduce sum(c*px), sum(c*py)
    const float c = (lane == 0) ? 0.0f : dinv * w0;
    float cx = c * p.x;
    float cy = c * p.y;
    #pragma unroll
    for (int off = 32; off > 0; off >>= 1) {
        cx += __shfl_xor(cx, off, 64);
        cy += __shfl_xor(cy, off, 64);
    }

    const float dinv0 = __shfl(dinv, 0, 64);
    const float px0 = sp[0].x;
    const float py0 = sp[0].y;

    if (lane < E) {
        const int e = lane;
        const float wg0 = W_gcn[e];
        const float wg1 = W_gcn[E + e];
        float agg = dinv0 * (cx * wg0 + cy * wg1)
                  + dinv0 * dinv0 * (px0 * wg0 + py0 * wg1);
        float enc = agg + b_gcn[e] + px0 * W_res[e] + py0 * W_res[E + e];
        out[3200 + g * E + e] = fmaxf(enc, 0.0f);
    }
    if (lane < F) {
        out[g * F + lane] = (lane == 0) ? px0 : py0;
    }
}

extern "C" void kernel_launch(void* const* d_in, const int* in_sizes, int n_in,
                              void* d_out, int out_size, void* d_ws, size_t ws_size,
                              hipStream_t stream) {
    const float* x     = (const float*)d_in[0];
    const float* W_res = (const float*)d_in[1];
    const float* W_gcn = (const float*)d_in[2];
    const float* b_gcn = (const float*)d_in[3];
    float* out = (float*)d_out;

    encoder_spatial_kernel<<<32 * 50, 64, 0, stream>>>(x, W_res, W_gcn, b_gcn, out);
}